// Round 6
// baseline (72.052 us; speedup 1.0000x reference)
//
#include <hip/hip_runtime.h>
#include <stdint.h>

// Problem constants (LSHSoftmax): B=1024, D=512, N=500000, S=32768
#define B_DIM 1024
#define D_DIM 512
#define S_DIM 32768

typedef __attribute__((ext_vector_type(8))) short bf16x8;   // 8 bf16 = 4 VGPRs
typedef __attribute__((ext_vector_type(4))) float f32x4;
typedef __attribute__((ext_vector_type(8))) unsigned short u16x8;

#define AS1 __attribute__((address_space(1)))
#define AS3 __attribute__((address_space(3)))

__device__ __forceinline__ unsigned short f2bf(float f) {
  union { float f; uint32_t u; } x; x.f = f;
  uint32_t r = x.u + 0x7fffu + ((x.u >> 16) & 1u);   // RNE
  return (unsigned short)(r >> 16);
}

// Fused prep: blocks [0, 8192) gather+convert W rows by ids; [8192, 8448) conv A.
#define GATHER_BLOCKS (S_DIM / 4)              // 8192
#define CONV_BLOCKS (B_DIM * D_DIM / 8 / 256)  // 256

__global__ __launch_bounds__(256) void prep(const float* __restrict__ W,
                                            const float* __restrict__ bias,
                                            const int* __restrict__ ids,
                                            const float* __restrict__ A,
                                            unsigned short* __restrict__ Wg,
                                            unsigned short* __restrict__ Ab,
                                            float* __restrict__ bg) {
  if (blockIdx.x < GATHER_BLOCKS) {
    int gid = blockIdx.x * 256 + threadIdx.x;
    int s = gid >> 6;
    int c = (gid & 63) * 8;
    int sid = ids[s];
    const float* src = W + (size_t)sid * D_DIM + c;
    float4 v0 = *(const float4*)src;
    float4 v1 = *(const float4*)(src + 4);
    u16x8 o;
    o[0] = f2bf(v0.x); o[1] = f2bf(v0.y); o[2] = f2bf(v0.z); o[3] = f2bf(v0.w);
    o[4] = f2bf(v1.x); o[5] = f2bf(v1.y); o[6] = f2bf(v1.z); o[7] = f2bf(v1.w);
    *(u16x8*)(Wg + (size_t)s * D_DIM + c) = o;
    if ((gid & 63) == 0) bg[s] = bias[sid];
  } else {
    int gid = (blockIdx.x - GATHER_BLOCKS) * 256 + threadIdx.x;
    const float* src = A + (size_t)gid * 8;
    float4 v0 = *(const float4*)src;
    float4 v1 = *(const float4*)(src + 4);
    u16x8 o;
    o[0] = f2bf(v0.x); o[1] = f2bf(v0.y); o[2] = f2bf(v0.z); o[3] = f2bf(v0.w);
    o[4] = f2bf(v1.x); o[5] = f2bf(v1.y); o[6] = f2bf(v1.z); o[7] = f2bf(v1.w);
    *(u16x8*)(Ab + (size_t)gid * 8) = o;
  }
}

// ---------------------------------------------------------------------------
// 8-phase 256x256 GEMM (T1+T2+T3+T4+T5): C[m,n] = sum_k Ab[m,k]*Wg[n,k]+bg[n]
// BK=64 split into 2 K-halves of 32 (the stage/release unit, 16 KB = 2
// global_load_lds per thread). 2 LDS buffers x (A 32K + B 32K) = 128 KiB.
// Per 8-phase iter: compute K-tiles t0 (buf0: ph0-3) and t1 (buf1: ph4-7);
// stage 8 half-units with provable region release:
//   ph0: t1.A.h1  ph1: t1.B.h1   (buf1 h1: last read prev-iter ph6/7)
//   ph2: t2.A.h0  ph3: t2.B.h0   (buf0 h0: released after ph1)
//   ph4: t2.A.h1  ph5: t2.B.h1   (buf0 h1: released after ph3)
//   ph6: t3.A.h0  ph7: t3.B.h0   (buf1 h0: released after ph5)
// Counted vmcnt per phase (2 loads/unit): N = 2*(units_issued - newest unit
// read by NEXT phase); steady state alternates 12/8, tail 8,4,6,0,2,0.
// LDS 16B-block permutation blk = row*4 + ((q + (row>>1)) & 3): conflict-free
// ds_read_b128 (8-lane groups hit distinct bank-groups), inverted on the
// pre-swizzled global source (gload_lds dest stays linear).
// ---------------------------------------------------------------------------
#define BM 256
#define BN 256
#define BK 64
#define NKT (D_DIM / BK)            // 8 K-tiles -> 4 main iters
#define AREG 32768                  // A region bytes per buffer
#define BUFBYTES 65536              // A + B per buffer

#define VMC(n) asm volatile("s_waitcnt vmcnt(" #n ")" ::: "memory")
__device__ __forceinline__ void vmcnt_sw(int n) {
  switch (n) {
    case 0:  VMC(0); break;
    case 2:  VMC(2); break;
    case 4:  VMC(4); break;
    case 6:  VMC(6); break;
    case 8:  VMC(8); break;
    case 10: VMC(10); break;
    default: VMC(12); break;
  }
}

__global__ __launch_bounds__(512, 2) void gemm_bias(const unsigned short* __restrict__ Ab,
                                                    const unsigned short* __restrict__ Wg,
                                                    const float* __restrict__ bg,
                                                    float* __restrict__ out) {
  __shared__ __attribute__((aligned(16))) char lds[2 * BUFBYTES];

  const int tid = threadIdx.x;
  const int lane = tid & 63;
  const int w = tid >> 6;          // wave 0..7
  const int wm = w >> 2;           // wave M 0..1 (128 rows each)
  const int wn = w & 3;            // wave N 0..3 (64 cols each)
  const int lq = lane >> 4;        // 0..3  (k-quarter within a half)
  const int l16 = lane & 15;

  // XCD swizzle: 512 blocks, 8 XCDs, 64 contiguous ids each; bm fastest so
  // 4 adjacent blocks share a B panel; 16 panels/XCD = 4 MB ~ L2.
  const int id = ((blockIdx.x & 7) << 6) | (blockIdx.x >> 3);
  const int m0 = (id & 3) * BM;
  const int n0 = (id >> 2) * BN;

  f32x4 acc[8][4];
#pragma unroll
  for (int m = 0; m < 8; ++m)
#pragma unroll
    for (int n = 0; n < 4; ++n)
      acc[m][n] = (f32x4)0.0f;

  // Stage one half-unit (16 KB): linear LDS dest, inverse-permuted source.
  // Physical slot P -> row = P>>2, q = ((P&3) - (row>>1)) & 3.
  auto stage_unit = [&](int tile, int isB, int half) {
    if (tile >= NKT) return;
    char* ubase = lds + (tile & 1) * BUFBYTES + isB * AREG + half * 16384;
    const unsigned short* gsrc = isB ? Wg : Ab;
    const int org = isB ? n0 : m0;
#pragma unroll
    for (int j = 0; j < 2; ++j) {
      const int slot = j * 512 + w * 64 + lane;
      const int row = slot >> 2;
      const int q = ((slot & 3) - (row >> 1)) & 3;
      const unsigned short* src = gsrc + (size_t)(org + row) * D_DIM
                                  + tile * BK + half * 32 + q * 8;
      __builtin_amdgcn_global_load_lds((const AS1 void*)src,
                                       (AS3 void*)(ubase + j * 8192 + w * 1024),
                                       16, 0, 0);
    }
  };

  // ---- Prologue: units u1..u6 ----
  stage_unit(0, 0, 0);  // t0.A.h0
  stage_unit(0, 1, 0);  // t0.B.h0
  stage_unit(0, 0, 1);  // t0.A.h1
  stage_unit(0, 1, 1);  // t0.B.h1
  stage_unit(1, 0, 0);  // t1.A.h0
  stage_unit(1, 1, 0);  // t1.B.h0
  VMC(8);               // u1,u2 (t0 h0) landed
  __builtin_amdgcn_s_barrier();

  // vmcnt table (loads): steady 12/8 alternation; exact tail (derived).
  static const int NTAB[4][8] = {
    {12, 8, 12, 8, 12, 8, 12, 8},
    {12, 8, 12, 8, 12, 8, 12, 8},
    {12, 8, 12, 8, 12, 8, 12, 8},
    {12, 8,  8, 4,  6, 0,  2, 0},
  };

#pragma unroll
  for (int i = 0; i < NKT / 2; ++i) {
#pragma unroll
    for (int t01 = 0; t01 < 2; ++t01) {
      const int tile = 2 * i + t01;
      const char* bufb = lds + (tile & 1) * BUFBYTES;
#pragma unroll
      for (int h = 0; h < 2; ++h) {
        bf16x8 bf[4];                       // B frags live across mg=0,1
#pragma unroll
        for (int mg = 0; mg < 2; ++mg) {
          const int ph = t01 * 4 + h * 2 + mg;

          // ---- ds-read this phase's fragments ----
          bf16x8 af[4];
          const char* Abase = bufb + h * 16384;
#pragma unroll
          for (int j = 0; j < 4; ++j) {
            const int rl = wm * 128 + mg * 64 + j * 16 + l16;
            const int blk = (rl << 2) + ((lq + (rl >> 1)) & 3);
            af[j] = *(const bf16x8*)(Abase + (blk << 4));
          }
          if (mg == 0) {
            const char* Bbase = bufb + AREG + h * 16384;
#pragma unroll
            for (int j = 0; j < 4; ++j) {
              const int cl = wn * 64 + j * 16 + l16;
              const int blk = (cl << 2) + ((lq + (cl >> 1)) & 3);
              bf[j] = *(const bf16x8*)(Bbase + (blk << 4));
            }
          }

          // ---- stage this phase's half-unit ----
          {
            const int stile = 2 * i + 1 + (ph >= 2) + (ph >= 6);
            const int sisB = ph & 1;
            const int shalf = 1 - ((ph >> 1) & 1);
            stage_unit(stile, sisB, shalf);
          }
          __builtin_amdgcn_sched_barrier(0);
          vmcnt_sw(NTAB[i][ph]);
          __builtin_amdgcn_s_barrier();                       // barrier 1
          asm volatile("s_waitcnt lgkmcnt(0)" ::: "memory");
          __builtin_amdgcn_sched_barrier(0);                  // rule #18

          __builtin_amdgcn_s_setprio(1);
#pragma unroll
          for (int j = 0; j < 4; ++j)
#pragma unroll
            for (int n = 0; n < 4; ++n)
              acc[mg * 4 + j][n] = __builtin_amdgcn_mfma_f32_16x16x32_bf16(
                  af[j], bf[n], acc[mg * 4 + j][n], 0, 0, 0);
          __builtin_amdgcn_s_setprio(0);
          __builtin_amdgcn_sched_barrier(0);
          __builtin_amdgcn_s_barrier();                       // barrier 2
        }
      }
    }
  }

  // ---- Epilogue: C[row][col] = acc + bias (col = l16, row = lq*4 + r) ----
  const int lrow = lq * 4;
#pragma unroll
  for (int n = 0; n < 4; ++n) {
    const int col = n0 + wn * 64 + n * 16 + l16;
    const float bvv = bg[col];
#pragma unroll
    for (int m = 0; m < 8; ++m) {
      const int rbase = m0 + wm * 128 + m * 16 + lrow;
#pragma unroll
      for (int r = 0; r < 4; ++r) {
        out[(size_t)(rbase + r) * S_DIM + col] = acc[m][n][r] + bvv;
      }
    }
  }
}

extern "C" void kernel_launch(void* const* d_in, const int* in_sizes, int n_in,
                              void* d_out, int out_size, void* d_ws, size_t ws_size,
                              hipStream_t stream) {
  const float* inp  = (const float*)d_in[0];   // [B, D] f32
  const float* W    = (const float*)d_in[1];   // [N, D] f32
  const float* bias = (const float*)d_in[2];   // [N] f32
  const int*   ids  = (const int*)d_in[3];     // [S] int32
  float* out = (float*)d_out;                  // [B, S] f32

  unsigned short* Wg = (unsigned short*)d_ws;                       // [S,D] bf16 (32 MiB)
  unsigned short* Ab = (unsigned short*)((char*)d_ws +
                        (size_t)S_DIM * D_DIM * 2);                 // [B,D] bf16 (1 MiB)
  float* bg = (float*)((char*)d_ws +
                        (size_t)S_DIM * D_DIM * 2 + (size_t)B_DIM * D_DIM * 2); // [S] f32

  prep<<<GATHER_BLOCKS + CONV_BLOCKS, 256, 0, stream>>>(W, bias, ids, inp, Wg, Ab, bg);

  dim3 grid((B_DIM / BM) * (S_DIM / BN));   // 4 * 128 = 512 blocks
  gemm_bias<<<grid, 512, 0, stream>>>(Ab, Wg, bg, out);
}